// Round 7
// baseline (1405.032 us; speedup 1.0000x reference)
//
#include <hip/hip_runtime.h>
#include <hip/hip_bf16.h>
#include <cstdint>
#include <cstddef>

#define N_NODES 50000
#define N_EDGES 640000
#define ET (N_EDGES + N_NODES)   // 690000 with self loops
#define IN_CH 128
#define H1 4
#define HC1 256                  // H1*C1
#define OUT_CH 64
#define SLOPE 0.2f
#define SCAN_NBLK ((N_NODES + 255) / 256)   // 196
#define XW (N_NODES * IN_CH / 8)            // 800000
#define W1N (IN_CH * HC1)                   // 32768
#define W2N (HC1 * OUT_CH)                  // 16384
#define CONVB ((XW + W1N + W2N + 255) / 256)  // 3317
#define EDGEB ((ET + 255) / 256)            // 2696
#define MT ((N_NODES + 63) / 64)            // 782
#define G1B (4 * MT)                        // 3128: NSUB=4 (64x64, B L1-resident)
#define AG1NB ((N_NODES + 3) / 4)           // 12500 agg blocks (4 nodes/block)

// fused_front block-range bases (dependency order)
#define FF_COUNT0 CONVB                       // 3317
#define FF_SCAN0  (CONVB + EDGEB)             // 6013
#define FF_GEMM0  (FF_SCAN0 + SCAN_NBLK)      // 6209
#define FF_FILL0  (FF_GEMM0 + G1B)            // 9337
#define FF_TOTAL  (FF_FILL0 + EDGEB)          // 12033

// fused_back block-range bases
#define FB_GEMM0  AG1NB                       // 12500
#define FB_AGG20  (AG1NB + MT)                // 13282
#define FB_TOTAL  (FB_AGG20 + AG1NB)          // 25782

// state slots (zeroed by memset each launch):
// [0] scan phase-1 counter   [1] scan phase-2 flag   [2] scan-done counter
// [3] agg1-done counter      [4] gemm2-done counter
// [5] conv-done counter      [6] count-done counter  [7] spare

typedef __attribute__((ext_vector_type(8))) short short8;
typedef __attribute__((ext_vector_type(4))) float floatx4;

__device__ __forceinline__ float bf2f(unsigned short u) {
    return __uint_as_float(((unsigned)u) << 16);
}
__device__ __forceinline__ unsigned short f2bf(float f) {
    unsigned u = __float_as_uint(f);
    unsigned r = 0x7fffu + ((u >> 16) & 1u);
    return (unsigned short)((u + r) >> 16);
}
__device__ __forceinline__ float ldf(const void* p, size_t i, bool f32) {
    return f32 ? ((const float*)p)[i] : bf2f(((const unsigned short*)p)[i]);
}
#define BLO(u) __uint_as_float((u) << 16)
#define BHI(u) __uint_as_float((u) & 0xffff0000u)

__device__ __forceinline__ void signal(int* p) {
    __hip_atomic_fetch_add(p, 1, __ATOMIC_RELEASE, __HIP_MEMORY_SCOPE_AGENT);
}
__device__ __forceinline__ void wait_for(int* p, int target) {
    if (threadIdx.x == 0) {
        while (__hip_atomic_load(p, __ATOMIC_ACQUIRE, __HIP_MEMORY_SCOPE_AGENT) < target)
            __builtin_amdgcn_s_sleep(8);
    }
    __syncthreads();
}

// x dtype probe: wave checks x[0..255] as bf16; garbage/huge => really f32.
__device__ __forceinline__ bool probe_f32(const unsigned short* x) {
    int t = threadIdx.x & 63;
    int bad = 0;
    #pragma unroll
    for (int r = 0; r < 4; ++r) {
        float v = bf2f(x[r * 64 + t]);
        if (!(v == v) || fabsf(v) > 1e4f) bad = 1;
    }
    unsigned long long m = __ballot(bad != 0);
    return m != 0ull;
}

// ---------------- MFMA bf16 GEMM body (NSUB=4: 16 KB B slice, L1-resident) ---
template <int KK, int NSUB>
__device__ __forceinline__ void gemm_body(
    const unsigned short* __restrict__ A, const unsigned short* __restrict__ Bt,
    const void* __restrict__ avs, const void* __restrict__ avd,
    const unsigned* __restrict__ flag, unsigned short* __restrict__ C,
    float* __restrict__ als, float* __restrict__ ald,
    int M, int N, int bx, int by)
{
    const int tid = threadIdx.x;
    const int m0 = by * 64, n0 = bx * (NSUB * 16);
    const int w = tid >> 6, lane = tid & 63;
    const int ln = lane & 15, quad = lane >> 4;
    const int m_frag = m0 + w * 16 + ln;
    floatx4 acc[NSUB];
    #pragma unroll
    for (int sub = 0; sub < NSUB; ++sub)
        acc[sub] = (floatx4){0.f, 0.f, 0.f, 0.f};

    for (int ks = 0; ks < KK / 32; ++ks) {
        const int kbase = ks * 32 + quad * 8;
        short8 a;
        if (m_frag < M) {
            a = *(const short8*)(A + (size_t)m_frag * KK + kbase);
        } else {
            #pragma unroll
            for (int j = 0; j < 8; ++j) a[j] = 0;
        }
        #pragma unroll
        for (int sub = 0; sub < NSUB; ++sub) {
            short8 b = *(const short8*)(Bt + (size_t)(n0 + sub * 16 + ln) * KK + kbase);
            acc[sub] = __builtin_amdgcn_mfma_f32_16x16x32_bf16(a, b, acc[sub], 0, 0, 0);
        }
    }

    #pragma unroll
    for (int sub = 0; sub < NSUB; ++sub) {
        #pragma unroll
        for (int r = 0; r < 4; ++r) {
            int m = m0 + w * 16 + quad * 4 + r;
            if (m < M)
                C[(size_t)m * N + n0 + sub * 16 + ln] = f2bf(acc[sub][r]);
        }
    }

    const bool f32in = (*flag != 0);
    float as[NSUB], av[NSUB];
    #pragma unroll
    for (int sub = 0; sub < NSUB; ++sub) {
        as[sub] = ldf(avs, n0 + sub * 16 + ln, f32in);
        av[sub] = ldf(avd, n0 + sub * 16 + ln, f32in);
    }
    const int Hh = N >> 6;
    #pragma unroll
    for (int hb = 0; hb < NSUB / 4; ++hb) {
        #pragma unroll
        for (int r = 0; r < 4; ++r) {
            float ps = 0.f, pd = 0.f;
            #pragma unroll
            for (int k = 0; k < 4; ++k) {
                ps += acc[hb * 4 + k][r] * as[hb * 4 + k];
                pd += acc[hb * 4 + k][r] * av[hb * 4 + k];
            }
            #pragma unroll
            for (int off = 1; off < 16; off <<= 1) {
                ps += __shfl_xor(ps, off, 64);
                pd += __shfl_xor(pd, off, 64);
            }
            int m = m0 + w * 16 + quad * 4 + r;
            if (ln == 0 && m < M) {
                als[(size_t)m * Hh + bx * (NSUB / 4) + hb] = ps;
                ald[(size_t)m * Hh + bx * (NSUB / 4) + hb] = pd;
            }
        }
    }
}

// ======= fused_front: conv || count -> scan -> gemm1 -> fill (one dispatch) ==
__global__ __launch_bounds__(256) void fused_front(
    const void* __restrict__ x, const void* __restrict__ W1,
    const void* __restrict__ W2, unsigned* __restrict__ flag,
    unsigned short* __restrict__ x16,
    unsigned short* __restrict__ Wt1, unsigned short* __restrict__ Wt2,
    const int* __restrict__ esrc, const int* __restrict__ edst,
    int* __restrict__ counts, int* __restrict__ epos,
    int* __restrict__ rowptr, int* __restrict__ bsum, int* __restrict__ boff,
    int* __restrict__ state,
    const void* __restrict__ as1, const void* __restrict__ ad1,
    unsigned short* __restrict__ h16,
    float* __restrict__ als1, float* __restrict__ ald1,
    int* __restrict__ ecsr)
{
    const int b = blockIdx.x;
    const int t = threadIdx.x;

    if (b < CONVB) {
        // ---- conv: x->bf16, W1^T, W2^T (inline dtype probe) ----
        const bool f32 = probe_f32((const unsigned short*)x);
        if (b == 0 && t == 0) *flag = f32 ? 1u : 0u;
        int i = b * 256 + t;
        if (i < XW) {
            size_t off = (size_t)i * 8;
            uint4 st;
            if (f32) {
                const float* xp = (const float*)x + off;
                float4 a = *(const float4*)xp;
                float4 c = *(const float4*)(xp + 4);
                st.x = (unsigned)f2bf(a.x) | ((unsigned)f2bf(a.y) << 16);
                st.y = (unsigned)f2bf(a.z) | ((unsigned)f2bf(a.w) << 16);
                st.z = (unsigned)f2bf(c.x) | ((unsigned)f2bf(c.y) << 16);
                st.w = (unsigned)f2bf(c.z) | ((unsigned)f2bf(c.w) << 16);
            } else {
                st = *(const uint4*)((const unsigned short*)x + off);
            }
            *(uint4*)(x16 + off) = st;
        } else if (i < XW + W1N) {
            int j = i - XW;                       // Wt1[n][k] = W1[k][n]
            int n = j / IN_CH, k = j % IN_CH;
            Wt1[j] = f2bf(ldf(W1, (size_t)k * HC1 + n, f32));
        } else if (i < XW + W1N + W2N) {
            int j = i - XW - W1N;                 // Wt2[n][k] = W2[k][n]
            int n = j / HC1, k = j % HC1;
            Wt2[j] = f2bf(ldf(W2, (size_t)k * OUT_CH + n, f32));
        }
        __syncthreads();
        if (t == 0) signal(&state[5]);            // conv-done
    } else if (b < FF_SCAN0) {
        // ---- count edges (+record slot) ----
        int i = (b - FF_COUNT0) * 256 + t;
        if (i < ET) {
            int d = (i < N_EDGES) ? edst[i] : (i - N_EDGES);
            epos[i] = atomicAdd(&counts[d], 1);
        }
        __syncthreads();
        if (t == 0) signal(&state[6]);            // count-done
    } else if (b < FF_GEMM0) {
        // ---- scan (waits count-done), R5-proven two-phase protocol ----
        wait_for(&state[6], EDGEB);
        __shared__ int s[256];
        const int bs = b - FF_SCAN0;
        const int i = bs * 256 + t;
        int v = (i < N_NODES) ? counts[i] : 0;
        s[t] = v;
        __syncthreads();
        #pragma unroll
        for (int off = 1; off < 256; off <<= 1) {
            int u = (t >= off) ? s[t - off] : 0;
            __syncthreads();
            s[t] += u;
            __syncthreads();
        }
        const int incl = s[t];
        if (t == 255) {
            __hip_atomic_store(&bsum[bs], incl, __ATOMIC_RELAXED, __HIP_MEMORY_SCOPE_AGENT);
            __hip_atomic_fetch_add(&state[0], 1, __ATOMIC_ACQ_REL, __HIP_MEMORY_SCOPE_AGENT);
        }
        if (bs == 0) {
            if (t == 0) {
                while (__hip_atomic_load(&state[0], __ATOMIC_ACQUIRE, __HIP_MEMORY_SCOPE_AGENT) < SCAN_NBLK)
                    __builtin_amdgcn_s_sleep(8);
            }
            __syncthreads();
            int w = (t < SCAN_NBLK)
                  ? __hip_atomic_load(&bsum[t], __ATOMIC_RELAXED, __HIP_MEMORY_SCOPE_AGENT) : 0;
            s[t] = w;
            __syncthreads();
            #pragma unroll
            for (int off = 1; off < 256; off <<= 1) {
                int u = (t >= off) ? s[t - off] : 0;
                __syncthreads();
                s[t] += u;
                __syncthreads();
            }
            if (t < SCAN_NBLK)
                __hip_atomic_store(&boff[t], s[t] - w, __ATOMIC_RELAXED, __HIP_MEMORY_SCOPE_AGENT);
            __syncthreads();
            if (t == 0)
                __hip_atomic_store(&state[1], 1, __ATOMIC_RELEASE, __HIP_MEMORY_SCOPE_AGENT);
        }
        if (t == 0) {
            while (__hip_atomic_load(&state[1], __ATOMIC_ACQUIRE, __HIP_MEMORY_SCOPE_AGENT) == 0)
                __builtin_amdgcn_s_sleep(8);
        }
        __syncthreads();
        int off0 = __hip_atomic_load(&boff[bs], __ATOMIC_RELAXED, __HIP_MEMORY_SCOPE_AGENT);
        if (i < N_NODES)
            __hip_atomic_store(&rowptr[i], off0 + incl - v,
                               __ATOMIC_RELAXED, __HIP_MEMORY_SCOPE_AGENT);
        if (i == N_NODES - 1)
            __hip_atomic_store(&rowptr[N_NODES], off0 + incl,
                               __ATOMIC_RELAXED, __HIP_MEMORY_SCOPE_AGENT);
        __syncthreads();
        if (t == 0) signal(&state[2]);            // scan-done
    } else if (b < FF_FILL0) {
        // ---- layer-1 GEMM (waits conv-done) ----
        wait_for(&state[5], CONVB);
        int g = b - FF_GEMM0;
        gemm_body<IN_CH, 4>(x16, Wt1, as1, ad1, flag, h16, als1, ald1,
                            N_NODES, HC1, g & 3, g >> 2);
    } else {
        // ---- fill_csr (waits scan-done; atomic-free slots) ----
        wait_for(&state[2], SCAN_NBLK);
        int i = (b - FF_FILL0) * 256 + t;
        if (i < ET) {
            int s = (i < N_EDGES) ? esrc[i] : (i - N_EDGES);
            int d = (i < N_EDGES) ? edst[i] : (i - N_EDGES);
            int rp = __hip_atomic_load(&rowptr[d], __ATOMIC_RELAXED, __HIP_MEMORY_SCOPE_AGENT);
            ecsr[rp + epos[i]] = s;
        }
    }
}

// ======= fused_back: agg1 -> gemm2 (waits) -> agg2 (waits), one dispatch =====
__global__ __launch_bounds__(256) void fused_back(
    const int* __restrict__ rowptr, const int* __restrict__ ecsr,
    const unsigned short* __restrict__ h16,
    const float* __restrict__ als1, const float* __restrict__ ald1,
    const void* __restrict__ b1, unsigned short* __restrict__ xo16,
    const unsigned short* __restrict__ Wt2,
    const void* __restrict__ as2, const void* __restrict__ ad2,
    unsigned short* __restrict__ h2,
    float* __restrict__ als2, float* __restrict__ ald2,
    const void* __restrict__ b2, const unsigned* __restrict__ flag,
    int* __restrict__ state, float* __restrict__ out)
{
    const int b = blockIdx.x;
    const int t = threadIdx.x;
    const int w = t >> 6, lane = t & 63;

    if (b < AG1NB) {
        // ---- agg1: R0-proven 4-wide loop + serial tail ----
        const int d = b * 4 + w;                   // exactly covers [0, N_NODES)
        const int hg = lane >> 4;
        const int c0 = (lane & 15) << 2;
        const int hoff = hg * 64 + c0;
        const int lo = rowptr[d], hi = rowptr[d + 1];
        const float ad = ald1[d * H1 + hg];

        float acc0 = 0.f, acc1 = 0.f, acc2 = 0.f, acc3 = 0.f, den = 0.f;

        int e = lo;
        for (; e + 3 < hi; e += 4) {
            int s0 = ecsr[e], s1 = ecsr[e + 1], s2 = ecsr[e + 2], s3 = ecsr[e + 3];
            uint2 q0 = *(const uint2*)(h16 + (size_t)s0 * HC1 + hoff);
            uint2 q1 = *(const uint2*)(h16 + (size_t)s1 * HC1 + hoff);
            uint2 q2 = *(const uint2*)(h16 + (size_t)s2 * HC1 + hoff);
            uint2 q3 = *(const uint2*)(h16 + (size_t)s3 * HC1 + hoff);
            float t0 = als1[s0 * H1 + hg] + ad;
            float t1 = als1[s1 * H1 + hg] + ad;
            float t2 = als1[s2 * H1 + hg] + ad;
            float t3 = als1[s3 * H1 + hg] + ad;
            float p0 = __expf(fmaxf(t0, SLOPE * t0));
            float p1 = __expf(fmaxf(t1, SLOPE * t1));
            float p2 = __expf(fmaxf(t2, SLOPE * t2));
            float p3 = __expf(fmaxf(t3, SLOPE * t3));
            den += (p0 + p1) + (p2 + p3);
            acc0 += p0 * BLO(q0.x) + p1 * BLO(q1.x) + p2 * BLO(q2.x) + p3 * BLO(q3.x);
            acc1 += p0 * BHI(q0.x) + p1 * BHI(q1.x) + p2 * BHI(q2.x) + p3 * BHI(q3.x);
            acc2 += p0 * BLO(q0.y) + p1 * BLO(q1.y) + p2 * BLO(q2.y) + p3 * BLO(q3.y);
            acc3 += p0 * BHI(q0.y) + p1 * BHI(q1.y) + p2 * BHI(q2.y) + p3 * BHI(q3.y);
        }
        for (; e < hi; ++e) {
            int s0 = ecsr[e];
            uint2 q0 = *(const uint2*)(h16 + (size_t)s0 * HC1 + hoff);
            float t0 = als1[s0 * H1 + hg] + ad;
            float p0 = __expf(fmaxf(t0, SLOPE * t0));
            den += p0;
            acc0 += p0 * BLO(q0.x);
            acc1 += p0 * BHI(q0.x);
            acc2 += p0 * BLO(q0.y);
            acc3 += p0 * BHI(q0.y);
        }

        const bool f32in = (*flag != 0);
        const float inv = 1.f / den;
        float v0 = acc0 * inv + ldf(b1, hoff + 0, f32in);
        float v1 = acc1 * inv + ldf(b1, hoff + 1, f32in);
        float v2 = acc2 * inv + ldf(b1, hoff + 2, f32in);
        float v3 = acc3 * inv + ldf(b1, hoff + 3, f32in);
        v0 = (v0 > 0.f) ? v0 : (__expf(v0) - 1.f);
        v1 = (v1 > 0.f) ? v1 : (__expf(v1) - 1.f);
        v2 = (v2 > 0.f) ? v2 : (__expf(v2) - 1.f);
        v3 = (v3 > 0.f) ? v3 : (__expf(v3) - 1.f);
        uint2 st;
        st.x = (unsigned)f2bf(v0) | ((unsigned)f2bf(v1) << 16);
        st.y = (unsigned)f2bf(v2) | ((unsigned)f2bf(v3) << 16);
        *(uint2*)(xo16 + (size_t)d * HC1 + hoff) = st;

        __syncthreads();
        if (t == 0) signal(&state[3]);             // agg1-done
    } else if (b < FB_AGG20) {
        // ---- gemm2 (waits all agg1) ----
        wait_for(&state[3], AG1NB);
        gemm_body<HC1, 4>(xo16, Wt2, as2, ad2, flag, h2, als2, ald2,
                          N_NODES, OUT_CH, 0, b - FB_GEMM0);
        __syncthreads();
        if (t == 0) signal(&state[4]);             // gemm2-done
    } else {
        // ---- agg2 (waits gemm2): R0-proven form ----
        wait_for(&state[4], MT);
        const int d = (b - FB_AGG20) * 4 + w;
        const int eg = lane >> 3;
        const int c0 = (lane & 7) << 3;
        const int lo = rowptr[d], hi = rowptr[d + 1];
        const float ad = ald2[d];

        float acc[8];
        #pragma unroll
        for (int j = 0; j < 8; ++j) acc[j] = 0.f;
        float den = 0.f;

        for (int eb = lo; eb < hi; eb += 8) {
            int e = eb + eg;
            if (e < hi) {
                int s = ecsr[e];
                uint4 q = *(const uint4*)(h2 + (size_t)s * OUT_CH + c0);
                float tt = als2[s] + ad;
                float p = __expf(fmaxf(tt, SLOPE * tt));
                den += p;
                acc[0] += p * BLO(q.x);
                acc[1] += p * BHI(q.x);
                acc[2] += p * BLO(q.y);
                acc[3] += p * BHI(q.y);
                acc[4] += p * BLO(q.z);
                acc[5] += p * BHI(q.z);
                acc[6] += p * BLO(q.w);
                acc[7] += p * BHI(q.w);
            }
        }
        #pragma unroll
        for (int off = 8; off <= 32; off <<= 1) {
            den += __shfl_xor(den, off, 64);
            #pragma unroll
            for (int j = 0; j < 8; ++j) acc[j] += __shfl_xor(acc[j], off, 64);
        }
        if (lane < 8) {
            const bool f32in = (*flag != 0);
            const float inv = 1.f / den;
            float4 v0, v1;
            v0.x = acc[0] * inv + ldf(b2, c0 + 0, f32in);
            v0.y = acc[1] * inv + ldf(b2, c0 + 1, f32in);
            v0.z = acc[2] * inv + ldf(b2, c0 + 2, f32in);
            v0.w = acc[3] * inv + ldf(b2, c0 + 3, f32in);
            v1.x = acc[4] * inv + ldf(b2, c0 + 4, f32in);
            v1.y = acc[5] * inv + ldf(b2, c0 + 5, f32in);
            v1.z = acc[6] * inv + ldf(b2, c0 + 6, f32in);
            v1.w = acc[7] * inv + ldf(b2, c0 + 7, f32in);
            *(float4*)(out + (size_t)d * OUT_CH + c0) = v0;
            *(float4*)(out + (size_t)d * OUT_CH + c0 + 4) = v1;
        }
    }
}

extern "C" void kernel_launch(void* const* d_in, const int* in_sizes, int n_in,
                              void* d_out, int out_size, void* d_ws, size_t ws_size,
                              hipStream_t stream)
{
    const void* x   = d_in[0];
    const void* W1  = d_in[1];
    const void* as1 = d_in[2];
    const void* ad1 = d_in[3];
    const void* b1  = d_in[4];
    const void* W2  = d_in[5];
    const void* as2 = d_in[6];
    const void* ad2 = d_in[7];
    const void* b2  = d_in[8];
    const int* esrc = (const int*)d_in[9];
    const int* edst = (const int*)d_in[10];
    float* out = (float*)d_out;  // [N,64] float32

    char* base = (char*)d_ws;
    const size_t MB = 1024 * 1024;
    unsigned short* x16  = (unsigned short*)(base);            // 12.8 MB [N,128] bf16
    unsigned short* h16  = (unsigned short*)(base + 13 * MB);  // 25.6 MB h1 [N,256] bf16
    unsigned short* xo16 = (unsigned short*)(base + 39 * MB);  // 25.6 MB x2 [N,256] bf16
    unsigned short* h2   = (unsigned short*)(base + 65 * MB);  //  6.4 MB h2 [N,64] bf16
    float* als1   = (float*)(base + 72 * MB);                  // 800 KB
    float* ald1   = (float*)(base + 73 * MB);                  // 800 KB
    float* als2   = (float*)(base + 74 * MB);                  // 200 KB
    float* ald2   = (float*)(base + 74 * MB + 512 * 1024);     // 200 KB
    unsigned short* Wt1 = (unsigned short*)(base + 75 * MB);   // 64 KB [256][128]
    unsigned short* Wt2 = (unsigned short*)(base + 75 * MB + 128 * 1024); // 32 KB
    int* counts   = (int*)(base + 76 * MB);                    // 200 KB
    int* state    = counts + N_NODES;                          // 8 ints (memset w/ counts)
    int* rowptr   = (int*)(base + 77 * MB);                    // 200 KB + 4 B
    int* bsum     = (int*)(base + 78 * MB);                    // small
    int* boff     = bsum + 256;
    unsigned* flag = (unsigned*)(base + 78 * MB + 8 * 1024);
    int* epos     = (int*)(base + 79 * MB);                    // 2.76 MB
    int* ecsr     = (int*)(base + 82 * MB);                    // 2.76 MB (exact)

    const int BLK = 256;

    // 1. zero counts + state[0..7] (single async memset, graph-capture safe)
    hipMemsetAsync(counts, 0, (size_t)N_NODES * 4 + 32, stream);

    // 2. fused front: conv || count -> scan -> gemm1 -> fill
    fused_front<<<FF_TOTAL, BLK, 0, stream>>>(
        x, W1, W2, flag, x16, Wt1, Wt2, esrc, edst, counts, epos,
        rowptr, bsum, boff, state, as1, ad1, h16, als1, ald1, ecsr);

    // 3. fused back: agg1 -> gemm2 -> agg2
    fused_back<<<FB_TOTAL, BLK, 0, stream>>>(
        rowptr, ecsr, h16, als1, ald1, b1, xo16, Wt2, as2, ad2,
        h2, als2, ald2, b2, flag, state, out);
}

// Round 9
// 297.384 us; speedup vs baseline: 4.7246x; 4.7246x over previous
//
#include <hip/hip_runtime.h>
#include <hip/hip_bf16.h>
#include <cstdint>
#include <cstddef>

#define N_NODES 50000
#define N_HALF 25000
#define N_EDGES 640000
#define ET (N_EDGES + N_NODES)   // 690000 with self loops
#define IN_CH 128
#define H1 4
#define HC1 256                  // H1*C1
#define OUT_CH 64
#define SLOPE 0.2f
#define SCAN_NBLK ((N_NODES + 255) / 256)   // 196
#define XW (N_NODES * IN_CH / 8)            // 800000
#define W1N (IN_CH * HC1)                   // 32768
#define W2N (HC1 * OUT_CH)                  // 16384
#define CONVB ((XW + W1N + W2N + 255) / 256)  // 3317
#define EDGEB ((ET + 255) / 256)            // 2696
#define MT ((N_NODES + 63) / 64)            // 782
#define G1B (4 * MT)                        // 3128: NSUB=4 (64x64, B L1-resident)
#define HALFB (N_HALF * 64 / 256)           // 6250 blocks per agg half

typedef __attribute__((ext_vector_type(8))) short short8;
typedef __attribute__((ext_vector_type(4))) float floatx4;

__device__ __forceinline__ float bf2f(unsigned short u) {
    return __uint_as_float(((unsigned)u) << 16);
}
__device__ __forceinline__ unsigned short f2bf(float f) {
    unsigned u = __float_as_uint(f);
    unsigned r = 0x7fffu + ((u >> 16) & 1u);
    return (unsigned short)((u + r) >> 16);
}
__device__ __forceinline__ float ldf(const void* p, size_t i, bool f32) {
    return f32 ? ((const float*)p)[i] : bf2f(((const unsigned short*)p)[i]);
}
#define BLO(u) __uint_as_float((u) << 16)
#define BHI(u) __uint_as_float((u) & 0xffff0000u)

// x dtype probe: wave checks x[0..255] as bf16; garbage/huge => really f32.
__device__ __forceinline__ bool probe_f32(const unsigned short* x) {
    int t = threadIdx.x & 63;
    int bad = 0;
    #pragma unroll
    for (int r = 0; r < 4; ++r) {
        float v = bf2f(x[r * 64 + t]);
        if (!(v == v) || fabsf(v) > 1e4f) bad = 1;
    }
    unsigned long long m = __ballot(bad != 0);
    return m != 0ull;
}

// ------- conv (x->bf16, W1^T, W2^T) || count edges (+record slot) ------------
__global__ __launch_bounds__(256) void conv_count(
    const void* __restrict__ x, const void* __restrict__ W1,
    const void* __restrict__ W2, unsigned* __restrict__ flag,
    unsigned short* __restrict__ x16,
    unsigned short* __restrict__ Wt1, unsigned short* __restrict__ Wt2,
    const int* __restrict__ edst, int* __restrict__ counts,
    int* __restrict__ epos)
{
    int b = blockIdx.x;
    if (b < CONVB) {
        const bool f32 = probe_f32((const unsigned short*)x);
        if (b == 0 && threadIdx.x == 0) *flag = f32 ? 1u : 0u;
        int i = b * 256 + threadIdx.x;
        if (i < XW) {
            size_t off = (size_t)i * 8;
            uint4 st;
            if (f32) {
                const float* xp = (const float*)x + off;
                float4 a = *(const float4*)xp;
                float4 c = *(const float4*)(xp + 4);
                st.x = (unsigned)f2bf(a.x) | ((unsigned)f2bf(a.y) << 16);
                st.y = (unsigned)f2bf(a.z) | ((unsigned)f2bf(a.w) << 16);
                st.z = (unsigned)f2bf(c.x) | ((unsigned)f2bf(c.y) << 16);
                st.w = (unsigned)f2bf(c.z) | ((unsigned)f2bf(c.w) << 16);
            } else {
                st = *(const uint4*)((const unsigned short*)x + off);
            }
            *(uint4*)(x16 + off) = st;
        } else if (i < XW + W1N) {
            int j = i - XW;                       // Wt1[n][k] = W1[k][n]
            int n = j / IN_CH, k = j % IN_CH;
            Wt1[j] = f2bf(ldf(W1, (size_t)k * HC1 + n, f32));
        } else if (i < XW + W1N + W2N) {
            int j = i - XW - W1N;                 // Wt2[n][k] = W2[k][n]
            int n = j / HC1, k = j % HC1;
            Wt2[j] = f2bf(ldf(W2, (size_t)k * OUT_CH + n, f32));
        }
    } else {
        int i = (b - CONVB) * 256 + threadIdx.x;
        if (i < ET) {
            int d = (i < N_EDGES) ? edst[i] : (i - N_EDGES);
            epos[i] = atomicAdd(&counts[d], 1);   // slot within bucket
        }
    }
}

// ---------------- single-dispatch two-phase scan (exact counts) --------------
__global__ __launch_bounds__(256) void scan_onepass(
    const int* __restrict__ counts, int* __restrict__ rowptr,
    int* __restrict__ bsum, int* __restrict__ boff, int* __restrict__ state)
{
    __shared__ int s[256];
    const int t = threadIdx.x, b = blockIdx.x;
    const int i = b * 256 + t;
    int v = (i < N_NODES) ? counts[i] : 0;
    s[t] = v;
    __syncthreads();
    #pragma unroll
    for (int off = 1; off < 256; off <<= 1) {
        int u = (t >= off) ? s[t - off] : 0;
        __syncthreads();
        s[t] += u;
        __syncthreads();
    }
    const int incl = s[t];
    if (t == 255) {
        __hip_atomic_store(&bsum[b], incl, __ATOMIC_RELAXED, __HIP_MEMORY_SCOPE_AGENT);
        __hip_atomic_fetch_add(&state[0], 1, __ATOMIC_ACQ_REL, __HIP_MEMORY_SCOPE_AGENT);
    }
    if (b == 0) {
        if (t == 0) {
            while (__hip_atomic_load(&state[0], __ATOMIC_ACQUIRE, __HIP_MEMORY_SCOPE_AGENT) < SCAN_NBLK)
                __builtin_amdgcn_s_sleep(8);
        }
        __syncthreads();
        int w = (t < SCAN_NBLK)
              ? __hip_atomic_load(&bsum[t], __ATOMIC_RELAXED, __HIP_MEMORY_SCOPE_AGENT) : 0;
        s[t] = w;
        __syncthreads();
        #pragma unroll
        for (int off = 1; off < 256; off <<= 1) {
            int u = (t >= off) ? s[t - off] : 0;
            __syncthreads();
            s[t] += u;
            __syncthreads();
        }
        if (t < SCAN_NBLK)
            __hip_atomic_store(&boff[t], s[t] - w, __ATOMIC_RELAXED, __HIP_MEMORY_SCOPE_AGENT);
        __syncthreads();
        if (t == 0)
            __hip_atomic_store(&state[1], 1, __ATOMIC_RELEASE, __HIP_MEMORY_SCOPE_AGENT);
    }
    if (t == 0) {
        while (__hip_atomic_load(&state[1], __ATOMIC_ACQUIRE, __HIP_MEMORY_SCOPE_AGENT) == 0)
            __builtin_amdgcn_s_sleep(8);
    }
    __syncthreads();
    int off0 = __hip_atomic_load(&boff[b], __ATOMIC_RELAXED, __HIP_MEMORY_SCOPE_AGENT);
    if (i < N_NODES)
        rowptr[i] = off0 + incl - v;   // exclusive
    if (i == N_NODES - 1) rowptr[N_NODES] = off0 + incl;   // == ET
}

// ---------------- MFMA bf16 GEMM body (NSUB=4: 16 KB B slice, L1-resident) ---
template <int KK, int NSUB>
__device__ __forceinline__ void gemm_body(
    const unsigned short* __restrict__ A, const unsigned short* __restrict__ Bt,
    const void* __restrict__ avs, const void* __restrict__ avd,
    const unsigned* __restrict__ flag, unsigned short* __restrict__ C,
    float* __restrict__ als, float* __restrict__ ald,
    int M, int N, int bx, int by)
{
    const int tid = threadIdx.x;
    const int m0 = by * 64, n0 = bx * (NSUB * 16);
    const int w = tid >> 6, lane = tid & 63;
    const int ln = lane & 15, quad = lane >> 4;
    const int m_frag = m0 + w * 16 + ln;
    floatx4 acc[NSUB];
    #pragma unroll
    for (int sub = 0; sub < NSUB; ++sub)
        acc[sub] = (floatx4){0.f, 0.f, 0.f, 0.f};

    for (int ks = 0; ks < KK / 32; ++ks) {
        const int kbase = ks * 32 + quad * 8;
        short8 a;
        if (m_frag < M) {
            a = *(const short8*)(A + (size_t)m_frag * KK + kbase);
        } else {
            #pragma unroll
            for (int j = 0; j < 8; ++j) a[j] = 0;
        }
        #pragma unroll
        for (int sub = 0; sub < NSUB; ++sub) {
            short8 b = *(const short8*)(Bt + (size_t)(n0 + sub * 16 + ln) * KK + kbase);
            acc[sub] = __builtin_amdgcn_mfma_f32_16x16x32_bf16(a, b, acc[sub], 0, 0, 0);
        }
    }

    #pragma unroll
    for (int sub = 0; sub < NSUB; ++sub) {
        #pragma unroll
        for (int r = 0; r < 4; ++r) {
            int m = m0 + w * 16 + quad * 4 + r;
            if (m < M)
                C[(size_t)m * N + n0 + sub * 16 + ln] = f2bf(acc[sub][r]);
        }
    }

    const bool f32in = (*flag != 0);
    float as[NSUB], av[NSUB];
    #pragma unroll
    for (int sub = 0; sub < NSUB; ++sub) {
        as[sub] = ldf(avs, n0 + sub * 16 + ln, f32in);
        av[sub] = ldf(avd, n0 + sub * 16 + ln, f32in);
    }
    const int Hh = N >> 6;
    #pragma unroll
    for (int hb = 0; hb < NSUB / 4; ++hb) {
        #pragma unroll
        for (int r = 0; r < 4; ++r) {
            float ps = 0.f, pd = 0.f;
            #pragma unroll
            for (int k = 0; k < 4; ++k) {
                ps += acc[hb * 4 + k][r] * as[hb * 4 + k];
                pd += acc[hb * 4 + k][r] * av[hb * 4 + k];
            }
            #pragma unroll
            for (int off = 1; off < 16; off <<= 1) {
                ps += __shfl_xor(ps, off, 64);
                pd += __shfl_xor(pd, off, 64);
            }
            int m = m0 + w * 16 + quad * 4 + r;
            if (ln == 0 && m < M) {
                als[(size_t)m * Hh + bx * (NSUB / 4) + hb] = ps;
                ald[(size_t)m * Hh + bx * (NSUB / 4) + hb] = pd;
            }
        }
    }
}

// -------- layer-1 GEMM (64x64 tiles) || fill_csr (atomic-free) ---------------
__global__ __launch_bounds__(256) void gemm1_fill(
    const unsigned short* __restrict__ x16, const unsigned short* __restrict__ Wt1,
    const void* __restrict__ as1, const void* __restrict__ ad1,
    const unsigned* __restrict__ flag, unsigned short* __restrict__ h16,
    float* __restrict__ als, float* __restrict__ ald,
    const int* __restrict__ esrc, const int* __restrict__ edst,
    const int* __restrict__ rowptr, const int* __restrict__ epos,
    int* __restrict__ ecsr)
{
    int b = blockIdx.x;
    if (b < G1B) {
        gemm_body<IN_CH, 4>(x16, Wt1, as1, ad1, flag, h16, als, ald,
                            N_NODES, HC1, b & 3, b >> 2);
    } else {
        int i = (b - G1B) * 256 + threadIdx.x;
        if (i < ET) {
            int s = (i < N_EDGES) ? esrc[i] : (i - N_EDGES);
            int d = (i < N_EDGES) ? edst[i] : (i - N_EDGES);
            ecsr[rowptr[d] + epos[i]] = s;   // no atomic: slot recorded in count
        }
    }
}

// ------- fused softmax + gather-aggregate, layer 1 (H=4): R0-proven form -----
// Half-range dispatch (node_base) so each instance drops below the middle
// kernels in the profile and top-5 reveals the rest of the pipeline.
__global__ __launch_bounds__(256) void agg_node1(
    const int* __restrict__ rowptr, const int* __restrict__ ecsr,
    const unsigned short* __restrict__ h, const float* __restrict__ als,
    const float* __restrict__ ald, const void* __restrict__ bias,
    const unsigned* __restrict__ flag, unsigned short* __restrict__ out,
    int node_base)
{
    int wave = (blockIdx.x * blockDim.x + threadIdx.x) >> 6;
    int lane = threadIdx.x & 63;
    if (wave >= N_HALF) return;
    const int d = node_base + wave;
    const int hg = lane >> 4;          // head
    const int c0 = (lane & 15) << 2;   // channel base
    const int hoff = hg * 64 + c0;
    const int lo = rowptr[d], hi = rowptr[d + 1];
    const float ad = ald[d * H1 + hg];

    float acc0 = 0.f, acc1 = 0.f, acc2 = 0.f, acc3 = 0.f, den = 0.f;

    int e = lo;
    for (; e + 3 < hi; e += 4) {
        int s0 = ecsr[e], s1 = ecsr[e + 1], s2 = ecsr[e + 2], s3 = ecsr[e + 3];
        uint2 q0 = *(const uint2*)(h + (size_t)s0 * HC1 + hoff);
        uint2 q1 = *(const uint2*)(h + (size_t)s1 * HC1 + hoff);
        uint2 q2 = *(const uint2*)(h + (size_t)s2 * HC1 + hoff);
        uint2 q3 = *(const uint2*)(h + (size_t)s3 * HC1 + hoff);
        float t0 = als[s0 * H1 + hg] + ad;
        float t1 = als[s1 * H1 + hg] + ad;
        float t2 = als[s2 * H1 + hg] + ad;
        float t3 = als[s3 * H1 + hg] + ad;
        float p0 = __expf(fmaxf(t0, SLOPE * t0));
        float p1 = __expf(fmaxf(t1, SLOPE * t1));
        float p2 = __expf(fmaxf(t2, SLOPE * t2));
        float p3 = __expf(fmaxf(t3, SLOPE * t3));
        den += (p0 + p1) + (p2 + p3);
        acc0 += p0 * BLO(q0.x) + p1 * BLO(q1.x) + p2 * BLO(q2.x) + p3 * BLO(q3.x);
        acc1 += p0 * BHI(q0.x) + p1 * BHI(q1.x) + p2 * BHI(q2.x) + p3 * BHI(q3.x);
        acc2 += p0 * BLO(q0.y) + p1 * BLO(q1.y) + p2 * BLO(q2.y) + p3 * BLO(q3.y);
        acc3 += p0 * BHI(q0.y) + p1 * BHI(q1.y) + p2 * BHI(q2.y) + p3 * BHI(q3.y);
    }
    for (; e < hi; ++e) {
        int s0 = ecsr[e];
        uint2 q0 = *(const uint2*)(h + (size_t)s0 * HC1 + hoff);
        float t0 = als[s0 * H1 + hg] + ad;
        float p0 = __expf(fmaxf(t0, SLOPE * t0));
        den += p0;
        acc0 += p0 * BLO(q0.x);
        acc1 += p0 * BHI(q0.x);
        acc2 += p0 * BLO(q0.y);
        acc3 += p0 * BHI(q0.y);
    }

    const bool f32in = (*flag != 0);
    const float inv = 1.f / den;
    float v0 = acc0 * inv + ldf(bias, hoff + 0, f32in);
    float v1 = acc1 * inv + ldf(bias, hoff + 1, f32in);
    float v2 = acc2 * inv + ldf(bias, hoff + 2, f32in);
    float v3 = acc3 * inv + ldf(bias, hoff + 3, f32in);
    v0 = (v0 > 0.f) ? v0 : (__expf(v0) - 1.f);
    v1 = (v1 > 0.f) ? v1 : (__expf(v1) - 1.f);
    v2 = (v2 > 0.f) ? v2 : (__expf(v2) - 1.f);
    v3 = (v3 > 0.f) ? v3 : (__expf(v3) - 1.f);
    uint2 st;
    st.x = (unsigned)f2bf(v0) | ((unsigned)f2bf(v1) << 16);
    st.y = (unsigned)f2bf(v2) | ((unsigned)f2bf(v3) << 16);
    *(uint2*)(out + (size_t)d * HC1 + hoff) = st;
}

// ---------------- layer-2 GEMM ----------------
__global__ __launch_bounds__(256) void gemm2(
    const unsigned short* __restrict__ xo16, const unsigned short* __restrict__ Wt2,
    const void* __restrict__ as2, const void* __restrict__ ad2,
    const unsigned* __restrict__ flag, unsigned short* __restrict__ h2,
    float* __restrict__ als, float* __restrict__ ald)
{
    gemm_body<HC1, 4>(xo16, Wt2, as2, ad2, flag, h2, als, ald,
                      N_NODES, OUT_CH, 0, blockIdx.x);
}

// ------- fused softmax + gather-aggregate, layer 2 (H=1): R0-proven form -----
__global__ __launch_bounds__(256) void agg_node2(
    const int* __restrict__ rowptr, const int* __restrict__ ecsr,
    const unsigned short* __restrict__ h, const float* __restrict__ als,
    const float* __restrict__ ald, const void* __restrict__ bias,
    const unsigned* __restrict__ flag, float* __restrict__ out,
    int node_base)
{
    int wave = (blockIdx.x * blockDim.x + threadIdx.x) >> 6;
    int lane = threadIdx.x & 63;
    if (wave >= N_HALF) return;
    const int d = node_base + wave;
    const int eg = lane >> 3;          // edge slot 0..7
    const int c0 = (lane & 7) << 3;    // channel base (8 channels)
    const int lo = rowptr[d], hi = rowptr[d + 1];
    const float ad = ald[d];

    float acc[8];
    #pragma unroll
    for (int j = 0; j < 8; ++j) acc[j] = 0.f;
    float den = 0.f;

    for (int eb = lo; eb < hi; eb += 8) {
        int e = eb + eg;
        if (e < hi) {
            int s = ecsr[e];
            uint4 q = *(const uint4*)(h + (size_t)s * OUT_CH + c0);
            float t = als[s] + ad;
            float p = __expf(fmaxf(t, SLOPE * t));
            den += p;
            acc[0] += p * BLO(q.x);
            acc[1] += p * BHI(q.x);
            acc[2] += p * BLO(q.y);
            acc[3] += p * BHI(q.y);
            acc[4] += p * BLO(q.z);
            acc[5] += p * BHI(q.z);
            acc[6] += p * BLO(q.w);
            acc[7] += p * BHI(q.w);
        }
    }
    #pragma unroll
    for (int off = 8; off <= 32; off <<= 1) {
        den += __shfl_xor(den, off, 64);
        #pragma unroll
        for (int j = 0; j < 8; ++j) acc[j] += __shfl_xor(acc[j], off, 64);
    }
    if (lane < 8) {
        const bool f32in = (*flag != 0);
        const float inv = 1.f / den;
        float4 v0, v1;
        v0.x = acc[0] * inv + ldf(bias, c0 + 0, f32in);
        v0.y = acc[1] * inv + ldf(bias, c0 + 1, f32in);
        v0.z = acc[2] * inv + ldf(bias, c0 + 2, f32in);
        v0.w = acc[3] * inv + ldf(bias, c0 + 3, f32in);
        v1.x = acc[4] * inv + ldf(bias, c0 + 4, f32in);
        v1.y = acc[5] * inv + ldf(bias, c0 + 5, f32in);
        v1.z = acc[6] * inv + ldf(bias, c0 + 6, f32in);
        v1.w = acc[7] * inv + ldf(bias, c0 + 7, f32in);
        *(float4*)(out + (size_t)d * OUT_CH + c0) = v0;
        *(float4*)(out + (size_t)d * OUT_CH + c0 + 4) = v1;
    }
}

extern "C" void kernel_launch(void* const* d_in, const int* in_sizes, int n_in,
                              void* d_out, int out_size, void* d_ws, size_t ws_size,
                              hipStream_t stream)
{
    const void* x   = d_in[0];
    const void* W1  = d_in[1];
    const void* as1 = d_in[2];
    const void* ad1 = d_in[3];
    const void* b1  = d_in[4];
    const void* W2  = d_in[5];
    const void* as2 = d_in[6];
    const void* ad2 = d_in[7];
    const void* b2  = d_in[8];
    const int* esrc = (const int*)d_in[9];
    const int* edst = (const int*)d_in[10];
    float* out = (float*)d_out;  // [N,64] float32

    char* base = (char*)d_ws;
    const size_t MB = 1024 * 1024;
    unsigned short* x16  = (unsigned short*)(base);            // 12.8 MB [N,128] bf16
    unsigned short* h16  = (unsigned short*)(base + 13 * MB);  // 25.6 MB h1 [N,256] bf16
    unsigned short* xo16 = (unsigned short*)(base + 39 * MB);  // 25.6 MB x2 [N,256] bf16
    unsigned short* h2   = (unsigned short*)(base + 65 * MB);  //  6.4 MB h2 [N,64] bf16
    float* als1   = (float*)(base + 72 * MB);                  // 800 KB
    float* ald1   = (float*)(base + 73 * MB);                  // 800 KB
    float* als2   = (float*)(base + 74 * MB);                  // 200 KB
    float* ald2   = (float*)(base + 74 * MB + 512 * 1024);     // 200 KB
    unsigned short* Wt1 = (unsigned short*)(base + 75 * MB);   // 64 KB [256][128]
    unsigned short* Wt2 = (unsigned short*)(base + 75 * MB + 128 * 1024); // 32 KB
    int* counts   = (int*)(base + 76 * MB);                    // 200 KB
    int* state    = counts + N_NODES;                          // ints (memset w/ counts)
    int* rowptr   = (int*)(base + 77 * MB);                    // 200 KB + 4 B
    int* bsum     = (int*)(base + 78 * MB);                    // small
    int* boff     = bsum + 256;
    unsigned* flag = (unsigned*)(base + 78 * MB + 8 * 1024);
    int* epos     = (int*)(base + 79 * MB);                    // 2.76 MB
    int* ecsr     = (int*)(base + 82 * MB);                    // 2.76 MB (exact)

    const int BLK = 256;

    // 1. zero counts + state (single async memset, graph-capture safe)
    hipMemsetAsync(counts, 0, (size_t)N_NODES * 4 + 32, stream);

    // 2. conv (x16, Wt1, Wt2; inline dtype probe) || count edges (slot in epos)
    conv_count<<<CONVB + EDGEB, BLK, 0, stream>>>(
        x, W1, W2, flag, x16, Wt1, Wt2, edst, counts, epos);

    // 3. single-dispatch scan (exact counts) -> rowptr
    scan_onepass<<<SCAN_NBLK, BLK, 0, stream>>>(
        counts, rowptr, bsum, boff, state);

    // 4. layer-1 GEMM (64x64 tiles, B L1-resident) || fill_csr
    gemm1_fill<<<G1B + EDGEB, BLK, 0, stream>>>(
        x16, Wt1, as1, ad1, flag, h16, als1, ald1, esrc, edst, rowptr, epos,
        ecsr);

    // 5a/5b. layer-1 aggregate (half-node dispatches for profile visibility)
    agg_node1<<<HALFB, BLK, 0, stream>>>(
        rowptr, ecsr, h16, als1, ald1, b1, flag, xo16, 0);
    agg_node1<<<HALFB, BLK, 0, stream>>>(
        rowptr, ecsr, h16, als1, ald1, b1, flag, xo16, N_HALF);

    // 6. layer-2 GEMM
    gemm2<<<MT, BLK, 0, stream>>>(xo16, Wt2, as2, ad2, flag, h2, als2, ald2);

    // 7a/7b. layer-2 aggregate -> out
    agg_node2<<<HALFB, BLK, 0, stream>>>(
        rowptr, ecsr, h2, als2, ald2, b2, flag, out, 0);
    agg_node2<<<HALFB, BLK, 0, stream>>>(
        rowptr, ecsr, h2, als2, ald2, b2, flag, out, N_HALF);
}